// Round 1
// baseline (381.361 us; speedup 1.0000x reference)
//
#include <hip/hip_runtime.h>
#include <math.h>

#define H 256
#define NR 14000
#define K1C 16
#define K2C 32
#define KT 48
#define CC 7
#define EPSF 1e-8f
#define GC1 128
#define CHUNK ((NR + GC1 - 1) / GC1)   // 110

__device__ __forceinline__ float rdlane(float v, int l) {
    return __int_as_float(__builtin_amdgcn_readlane(__float_as_int(v), l));
}

__device__ __forceinline__ float dot4(const float4 a, const float4 b) {
    return a.x * b.x + a.y * b.y + a.z * b.z + a.w * b.w;
}

// ---------------- Kernel A: gather + cosine softmax + weighted sum ----------
// One wave per n. 4 groups of 16 lanes; each group processes one neighbor row
// at a time (group g handles k = 4*kk + g). Each group's 16 lanes hold a full
// copy of the 256-dim vectors (16 floats/lane: h = 4*l + 64*j + m).
// Fixed-shift softmax: sims are cosines in [-1,1] -> exp(s-1) is stable.
__global__ __launch_bounds__(256) void kA(
    const float* __restrict__ embeds, const float* __restrict__ w_self,
    const float* __restrict__ w_n, const float* __restrict__ w_n2,
    const int* __restrict__ idx, const int* __restrict__ nbr1,
    const int* __restrict__ nbr2, float* __restrict__ inbuf,
    float* __restrict__ cebuf)
{
    const int tid = threadIdx.x;
    const int wv = tid >> 6, lane = tid & 63;
    const int n = blockIdx.x * 4 + wv;
    const int g = lane >> 4, l = lane & 15;
    const int hb = l * 4;

    float4 wn4[4], wn24[4], ce4[4];
    float na2 = 0.f;
    const int cidx = idx[n];
    const float* crow = embeds + (size_t)cidx * H;
#pragma unroll
    for (int j = 0; j < 4; ++j) {
        const float4 wsv = *(const float4*)(w_self + hb + 64 * j);
        wn4[j]  = *(const float4*)(w_n  + hb + 64 * j);
        wn24[j] = *(const float4*)(w_n2 + hb + 64 * j);
        const float4 cv = *(const float4*)(crow + hb + 64 * j);
        float4 ce;
        ce.x = wsv.x * cv.x; ce.y = wsv.y * cv.y;
        ce.z = wsv.z * cv.z; ce.w = wsv.w * cv.w;
        ce4[j] = ce;
        na2 += dot4(ce, ce);
    }
#pragma unroll
    for (int m = 1; m <= 8; m <<= 1) na2 += __shfl_xor(na2, m);
    const float na = fmaxf(sqrtf(na2), EPSF);

    int ridx = 0;
    if (lane < K1C) ridx = nbr1[n * K1C + lane];
    else if (lane < KT) ridx = nbr2[n * K2C + (lane - K1C)];

    float4 acc[4];
#pragma unroll
    for (int j = 0; j < 4; ++j) acc[j] = make_float4(0.f, 0.f, 0.f, 0.f);
    float lsum = 0.f;

#pragma unroll
    for (int kk = 0; kk < 12; ++kk) {
        const int row = __shfl(ridx, kk * 4 + g);
        const float* rp = embeds + (size_t)row * H;
        float num = 0.f, nn = 0.f;
        float4 nb4[4];
#pragma unroll
        for (int j = 0; j < 4; ++j) {
            const float4 ev = *(const float4*)(rp + hb + 64 * j);
            const float4 wv4 = (kk < 4) ? wn4[j] : wn24[j];  // compile-time after unroll
            float4 nb;
            nb.x = wv4.x * ev.x; nb.y = wv4.y * ev.y;
            nb.z = wv4.z * ev.z; nb.w = wv4.w * ev.w;
            nb4[j] = nb;
            num += dot4(ce4[j], nb);
            nn  += dot4(nb, nb);
        }
#pragma unroll
        for (int m = 1; m <= 8; m <<= 1) {
            num += __shfl_xor(num, m);
            nn  += __shfl_xor(nn, m);
        }
        const float nbn = fmaxf(sqrtf(nn), EPSF);
        const float sim = num / (nbn * na);
        const float e = __expf(sim - 1.0f);   // fixed-shift softmax (sim <= 1)
        lsum += e;
#pragma unroll
        for (int j = 0; j < 4; ++j) {
            acc[j].x += e * nb4[j].x; acc[j].y += e * nb4[j].y;
            acc[j].z += e * nb4[j].z; acc[j].w += e * nb4[j].w;
        }
    }
    // merge the 4 groups (each holds a full h-copy of its partial sums)
#pragma unroll
    for (int m = 16; m <= 32; m <<= 1) {
        lsum += __shfl_xor(lsum, m);
#pragma unroll
        for (int j = 0; j < 4; ++j) {
            acc[j].x += __shfl_xor(acc[j].x, m);
            acc[j].y += __shfl_xor(acc[j].y, m);
            acc[j].z += __shfl_xor(acc[j].z, m);
            acc[j].w += __shfl_xor(acc[j].w, m);
        }
    }
    const float rl = 1.0f / lsum;
    if (g == 0) {
        float* ip = inbuf + (size_t)n * H;
        float* cp = cebuf + (size_t)n * H;
#pragma unroll
        for (int j = 0; j < 4; ++j) {
            float4 iv;
            iv.x = acc[j].x * rl + ce4[j].x;
            iv.y = acc[j].y * rl + ce4[j].y;
            iv.z = acc[j].z * rl + ce4[j].z;
            iv.w = acc[j].w * rl + ce4[j].w;
            *(float4*)(ip + hb + 64 * j) = iv;
            *(float4*)(cp + hb + 64 * j) = ce4[j];
        }
    }
}

// ---------------- Kernel B: adapter rawret = elu(in@W1+b1)@W2 + b2 + ce -----
// 8 rows per wave, lane = b for matmul1 (W1 swizzle-transposed in 64KB LDS),
// lane = h-chunk for matmul2 (W2 from global, L2-resident). Broadcasts via
// v_readlane (SGPR operand -> no LDS-pipe cost). Writes rawret over inputs.
__global__ __launch_bounds__(256) void kB(
    float* io, const float* __restrict__ cebuf,
    const float* __restrict__ W1, const float* __restrict__ b1,
    const float* __restrict__ W2, const float* __restrict__ b2)
{
    __shared__ float W1T[64 * 256];   // [b][h], 16B chunks XOR-swizzled by (b&15)
    const int tid = threadIdx.x;
    {
        const int b = tid & 63, hblk = tid >> 6;
        for (int hh = 0; hh < 64; ++hh) {
            const int h = hblk * 64 + hh;
            const int chunk = (h >> 2) ^ (b & 15);
            W1T[b * 256 + chunk * 4 + (h & 3)] = W1[h * 64 + b];
        }
    }
    __syncthreads();

    const int wv = tid >> 6, lane = tid & 63;
    const int r0 = (blockIdx.x * 4 + wv) * 8;
    if (r0 >= NR) return;
    const int nr = min(8, NR - r0);

    float4 in4[8];
#pragma unroll
    for (int r = 0; r < 8; ++r) in4[r] = make_float4(0.f, 0.f, 0.f, 0.f);
    for (int r = 0; r < nr; ++r)
        in4[r] = *(const float4*)(io + (size_t)(r0 + r) * H + 4 * lane);

    float hid[8];
    const float bb = b1[lane];
#pragma unroll
    for (int r = 0; r < 8; ++r) hid[r] = bb;

    for (int h4 = 0; h4 < 64; ++h4) {
        const float4 w1v = *(const float4*)(&W1T[lane * 256 + 4 * (h4 ^ (lane & 15))]);
#pragma unroll
        for (int j = 0; j < 4; ++j) {
            const float wj = (j == 0) ? w1v.x : (j == 1) ? w1v.y : (j == 2) ? w1v.z : w1v.w;
#pragma unroll
            for (int r = 0; r < 8; ++r) {
                const float src = (j == 0) ? in4[r].x : (j == 1) ? in4[r].y
                                 : (j == 2) ? in4[r].z : in4[r].w;
                hid[r] += rdlane(src, h4) * wj;
            }
        }
    }
#pragma unroll
    for (int r = 0; r < 8; ++r)
        hid[r] = hid[r] > 0.f ? hid[r] : (__expf(hid[r]) - 1.0f);  // elu

    float4 p4[8];
    const float4 b2v = *(const float4*)(b2 + 4 * lane);
#pragma unroll
    for (int r = 0; r < 8; ++r) p4[r] = b2v;
    for (int b = 0; b < 64; ++b) {
        const float4 w2v = *(const float4*)(W2 + b * H + 4 * lane);
#pragma unroll
        for (int r = 0; r < 8; ++r) {
            const float hv = rdlane(hid[r], b);
            p4[r].x += hv * w2v.x; p4[r].y += hv * w2v.y;
            p4[r].z += hv * w2v.z; p4[r].w += hv * w2v.w;
        }
    }
    for (int r = 0; r < nr; ++r) {
        const float4 cev = *(const float4*)(cebuf + (size_t)(r0 + r) * H + 4 * lane);
        float4 ov;
        ov.x = p4[r].x + cev.x; ov.y = p4[r].y + cev.y;
        ov.z = p4[r].z + cev.z; ov.w = p4[r].w + cev.w;
        *(float4*)(io + (size_t)(r0 + r) * H + 4 * lane) = ov;
    }
}

// ---------------- Kernel C1: per-chunk per-class partial sums ---------------
__global__ __launch_bounds__(256) void kC1(
    const float* __restrict__ rawret, const int* __restrict__ labels,
    float* __restrict__ partial)
{
    const int t = threadIdx.x, j = blockIdx.x;
    const int nlo = j * CHUNK;
    const int nhi = min(nlo + CHUNK, NR);
    float acc[CC];
#pragma unroll
    for (int c = 0; c < CC; ++c) acc[c] = 0.f;
    for (int n = nlo; n < nhi; ++n) {
        const int lab = labels[n];
        const float v = rawret[(size_t)n * H + t];
#pragma unroll
        for (int c = 0; c < CC; ++c) acc[c] += (lab == c) ? v : 0.f;
    }
#pragma unroll
    for (int c = 0; c < CC; ++c) partial[(size_t)(j * CC + c) * H + t] = acc[c];
}

// ---------------- Kernel C2: finalize class means + norms -------------------
__global__ __launch_bounds__(256) void kC2(
    const float* __restrict__ partial, float* __restrict__ ave,
    float* __restrict__ anorm)
{
    const int c = blockIdx.x, t = threadIdx.x;
    float s = 0.f;
    for (int j = 0; j < GC1; ++j) s += partial[(size_t)(j * CC + c) * H + t];
    const float a = s * (1.0f / 2000.0f);   // per_class = N // C
    ave[c * H + t] = a;
    __shared__ float red[256];
    red[t] = a * a;
    __syncthreads();
    for (int m = 128; m > 0; m >>= 1) {
        if (t < m) red[t] += red[t + m];
        __syncthreads();
    }
    if (t == 0) anorm[c] = fmaxf(sqrtf(red[0]), EPSF);
}

// ---------------- Kernel D: class-cosine softmax -> out [N,7] ---------------
__global__ __launch_bounds__(256) void kD(
    const float* __restrict__ rawret, const float* __restrict__ ave,
    const float* __restrict__ anorm, float* __restrict__ out)
{
    const int tid = threadIdx.x;
    const int wv = tid >> 6, lane = tid & 63;
    const int n = blockIdx.x * 4 + wv;
    const float4 r4 = *(const float4*)(rawret + (size_t)n * H + 4 * lane);
    float nr2 = dot4(r4, r4);
#pragma unroll
    for (int m = 1; m <= 32; m <<= 1) nr2 += __shfl_xor(nr2, m);
    const float rn = fmaxf(sqrtf(nr2), EPSF);

    float e[CC];
    float s = 0.f;
#pragma unroll
    for (int c = 0; c < CC; ++c) {
        const float4 a4 = *(const float4*)(ave + c * H + 4 * lane);
        float d = dot4(r4, a4);
#pragma unroll
        for (int m = 1; m <= 32; m <<= 1) d += __shfl_xor(d, m);
        const float sim = d / (rn * anorm[c]);
        e[c] = __expf(sim - 1.0f);   // fixed-shift softmax (|sim| <= 1)
        s += e[c];
    }
    const float rs = 1.0f / s;
    if (lane < CC) {
        float v = e[0];
#pragma unroll
        for (int c = 1; c < CC; ++c) v = (lane == c) ? e[c] : v;
        out[(size_t)n * CC + lane] = v * rs;
    }
}

extern "C" void kernel_launch(void* const* d_in, const int* in_sizes, int n_in,
                              void* d_out, int out_size, void* d_ws, size_t ws_size,
                              hipStream_t stream) {
    const float* embeds = (const float*)d_in[0];
    const float* w_self = (const float*)d_in[1];
    const float* w_n    = (const float*)d_in[2];
    const float* w_n2   = (const float*)d_in[3];
    const float* W1     = (const float*)d_in[4];
    const float* b1     = (const float*)d_in[5];
    const float* W2     = (const float*)d_in[6];
    const float* b2     = (const float*)d_in[7];
    const int* idx      = (const int*)d_in[8];
    const int* nbr1     = (const int*)d_in[9];
    const int* nbr2     = (const int*)d_in[10];
    const int* labels   = (const int*)d_in[11];
    float* out = (float*)d_out;

    float* buf0    = (float*)d_ws;                       // N*H: inputs -> rawret
    float* buf1    = buf0 + (size_t)NR * H;              // N*H: ce
    float* partial = buf1 + (size_t)NR * H;              // GC1*7*H
    float* ave     = partial + (size_t)GC1 * CC * H;     // 7*H
    float* anorm   = ave + (size_t)CC * H;               // 7

    kA<<<NR / 4, 256, 0, stream>>>(embeds, w_self, w_n, w_n2, idx, nbr1, nbr2,
                                   buf0, buf1);
    kB<<<(NR + 31) / 32, 256, 0, stream>>>(buf0, buf1, W1, b1, W2, b2);
    kC1<<<GC1, 256, 0, stream>>>(buf0, labels, partial);
    kC2<<<CC, 256, 0, stream>>>(partial, ave, anorm);
    kD<<<NR / 4, 256, 0, stream>>>(buf0, ave, anorm, out);
}

// Round 2
// 328.389 us; speedup vs baseline: 1.1613x; 1.1613x over previous
//
#include <hip/hip_runtime.h>
#include <hip/hip_bf16.h>
#include <math.h>

#define H 256
#define NR 14000
#define MR 100000
#define K1C 16
#define K2C 32
#define KT 48
#define CC 7
#define EPSF 1e-8f
#define GC1 128
#define CHUNK ((NR + GC1 - 1) / GC1)   // 110

typedef __attribute__((ext_vector_type(8))) unsigned short ushort8_t;

__device__ __forceinline__ float rdlane(float v, int l) {
    return __int_as_float(__builtin_amdgcn_readlane(__float_as_int(v), l));
}

__device__ __forceinline__ float dot4(const float4 a, const float4 b) {
    return a.x * b.x + a.y * b.y + a.z * b.z + a.w * b.w;
}

__device__ __forceinline__ unsigned short f2bf(float x) {
    __hip_bfloat16 h = __float2bfloat16(x);   // round-to-nearest
    return *(unsigned short*)&h;
}

// ---------------- Kernel E: fp32 table -> bf16 table (RN) -------------------
__global__ __launch_bounds__(256) void kE(const float* __restrict__ src,
                                          unsigned short* __restrict__ dst) {
    const size_t base = ((size_t)blockIdx.x * 256 + threadIdx.x) * 8;
    const float4 a = *(const float4*)(src + base);
    const float4 b = *(const float4*)(src + base + 4);
    ushort8_t o;
    o[0] = f2bf(a.x); o[1] = f2bf(a.y); o[2] = f2bf(a.z); o[3] = f2bf(a.w);
    o[4] = f2bf(b.x); o[5] = f2bf(b.y); o[6] = f2bf(b.z); o[7] = f2bf(b.w);
    *(ushort8_t*)(dst + base) = o;
}

// ---------------- Kernel A2: bf16 gather + cosine softmax + weighted sum ----
// One wave per n. 4 groups of 16 lanes; group g handles neighbor k = 4*kk+g.
// Lane l of a group owns h in [16l, 16l+16). Neighbor rows gathered from the
// bf16 table (halved traffic); center row from the fp32 table (14 MB, exact).
// Fixed-shift softmax: sims are cosines <= 1 -> exp(s-1) stable, single pass.
__global__ __launch_bounds__(256) void kA2(
    const float* __restrict__ embeds, const unsigned short* __restrict__ ebf,
    const float* __restrict__ w_self, const float* __restrict__ w_n,
    const float* __restrict__ w_n2, const int* __restrict__ idx,
    const int* __restrict__ nbr1, const int* __restrict__ nbr2,
    float* __restrict__ inbuf, float* __restrict__ cebuf)
{
    const int tid = threadIdx.x;
    const int wv = tid >> 6, lane = tid & 63;
    const int n = blockIdx.x * 4 + wv;
    const int g = lane >> 4, l = lane & 15;
    const int hb = l * 16;

    float ce[16], wn[16], wn2[16];
    float na2 = 0.f;
    const int cidx = idx[n];
    const float* crow = embeds + (size_t)cidx * H + hb;
#pragma unroll
    for (int j = 0; j < 4; ++j) {
        const float4 wsv  = *(const float4*)(w_self + hb + 4 * j);
        const float4 wnv  = *(const float4*)(w_n    + hb + 4 * j);
        const float4 wn2v = *(const float4*)(w_n2   + hb + 4 * j);
        const float4 cv   = *(const float4*)(crow + 4 * j);
        wn[4*j+0] = wnv.x;  wn[4*j+1] = wnv.y;  wn[4*j+2] = wnv.z;  wn[4*j+3] = wnv.w;
        wn2[4*j+0] = wn2v.x; wn2[4*j+1] = wn2v.y; wn2[4*j+2] = wn2v.z; wn2[4*j+3] = wn2v.w;
        ce[4*j+0] = wsv.x * cv.x; ce[4*j+1] = wsv.y * cv.y;
        ce[4*j+2] = wsv.z * cv.z; ce[4*j+3] = wsv.w * cv.w;
        na2 += ce[4*j+0]*ce[4*j+0] + ce[4*j+1]*ce[4*j+1]
             + ce[4*j+2]*ce[4*j+2] + ce[4*j+3]*ce[4*j+3];
    }
#pragma unroll
    for (int m = 1; m <= 8; m <<= 1) na2 += __shfl_xor(na2, m);
    const float na = fmaxf(sqrtf(na2), EPSF);

    int ridx = 0;
    if (lane < K1C) ridx = nbr1[n * K1C + lane];
    else if (lane < KT) ridx = nbr2[n * K2C + (lane - K1C)];

    float acc[16];
#pragma unroll
    for (int i = 0; i < 16; ++i) acc[i] = 0.f;
    float lsum = 0.f;

#pragma unroll
    for (int kk = 0; kk < 12; ++kk) {
        const int row = __shfl(ridx, kk * 4 + g);
        const unsigned short* rp = ebf + (size_t)row * H + hb;
        const ushort8_t e0 = *(const ushort8_t*)(rp);
        const ushort8_t e1 = *(const ushort8_t*)(rp + 8);
        float nb[16];
#pragma unroll
        for (int i = 0; i < 8; ++i) {
            nb[i]     = __uint_as_float((unsigned)e0[i] << 16);
            nb[8 + i] = __uint_as_float((unsigned)e1[i] << 16);
        }
        float num = 0.f, nn = 0.f;
#pragma unroll
        for (int i = 0; i < 16; ++i) {
            const float w = (kk < 4) ? wn[i] : wn2[i];  // compile-time after unroll
            nb[i] *= w;
            num += ce[i] * nb[i];
            nn  += nb[i] * nb[i];
        }
#pragma unroll
        for (int m = 1; m <= 8; m <<= 1) {
            num += __shfl_xor(num, m);
            nn  += __shfl_xor(nn, m);
        }
        const float nbn = fmaxf(sqrtf(nn), EPSF);
        const float e = __expf(num / (nbn * na) - 1.0f);
        lsum += e;
#pragma unroll
        for (int i = 0; i < 16; ++i) acc[i] += e * nb[i];
    }
    // merge the 4 groups (lanes with equal l hold the same h-range)
#pragma unroll
    for (int m = 16; m <= 32; m <<= 1) {
        lsum += __shfl_xor(lsum, m);
#pragma unroll
        for (int i = 0; i < 16; ++i) acc[i] += __shfl_xor(acc[i], m);
    }
    const float rl = 1.0f / lsum;
    if (g == 0) {
        float* ip = inbuf + (size_t)n * H + hb;
        float* cp = cebuf + (size_t)n * H + hb;
#pragma unroll
        for (int i = 0; i < 16; ++i) {
            ip[i] = acc[i] * rl + ce[i];
            cp[i] = ce[i];
        }
    }
}

// ---------------- Kernel A (fp32 fallback, layout from round 1) -------------
__global__ __launch_bounds__(256) void kA(
    const float* __restrict__ embeds, const float* __restrict__ w_self,
    const float* __restrict__ w_n, const float* __restrict__ w_n2,
    const int* __restrict__ idx, const int* __restrict__ nbr1,
    const int* __restrict__ nbr2, float* __restrict__ inbuf,
    float* __restrict__ cebuf)
{
    const int tid = threadIdx.x;
    const int wv = tid >> 6, lane = tid & 63;
    const int n = blockIdx.x * 4 + wv;
    const int g = lane >> 4, l = lane & 15;
    const int hb = l * 4;

    float4 wn4[4], wn24[4], ce4[4];
    float na2 = 0.f;
    const int cidx = idx[n];
    const float* crow = embeds + (size_t)cidx * H;
#pragma unroll
    for (int j = 0; j < 4; ++j) {
        const float4 wsv = *(const float4*)(w_self + hb + 64 * j);
        wn4[j]  = *(const float4*)(w_n  + hb + 64 * j);
        wn24[j] = *(const float4*)(w_n2 + hb + 64 * j);
        const float4 cv = *(const float4*)(crow + hb + 64 * j);
        float4 ce;
        ce.x = wsv.x * cv.x; ce.y = wsv.y * cv.y;
        ce.z = wsv.z * cv.z; ce.w = wsv.w * cv.w;
        ce4[j] = ce;
        na2 += dot4(ce, ce);
    }
#pragma unroll
    for (int m = 1; m <= 8; m <<= 1) na2 += __shfl_xor(na2, m);
    const float na = fmaxf(sqrtf(na2), EPSF);

    int ridx = 0;
    if (lane < K1C) ridx = nbr1[n * K1C + lane];
    else if (lane < KT) ridx = nbr2[n * K2C + (lane - K1C)];

    float4 acc[4];
#pragma unroll
    for (int j = 0; j < 4; ++j) acc[j] = make_float4(0.f, 0.f, 0.f, 0.f);
    float lsum = 0.f;

#pragma unroll
    for (int kk = 0; kk < 12; ++kk) {
        const int row = __shfl(ridx, kk * 4 + g);
        const float* rp = embeds + (size_t)row * H;
        float num = 0.f, nn = 0.f;
        float4 nb4[4];
#pragma unroll
        for (int j = 0; j < 4; ++j) {
            const float4 ev = *(const float4*)(rp + hb + 64 * j);
            const float4 wv4 = (kk < 4) ? wn4[j] : wn24[j];
            float4 nb;
            nb.x = wv4.x * ev.x; nb.y = wv4.y * ev.y;
            nb.z = wv4.z * ev.z; nb.w = wv4.w * ev.w;
            nb4[j] = nb;
            num += dot4(ce4[j], nb);
            nn  += dot4(nb, nb);
        }
#pragma unroll
        for (int m = 1; m <= 8; m <<= 1) {
            num += __shfl_xor(num, m);
            nn  += __shfl_xor(nn, m);
        }
        const float nbn = fmaxf(sqrtf(nn), EPSF);
        const float e = __expf(num / (nbn * na) - 1.0f);
        lsum += e;
#pragma unroll
        for (int j = 0; j < 4; ++j) {
            acc[j].x += e * nb4[j].x; acc[j].y += e * nb4[j].y;
            acc[j].z += e * nb4[j].z; acc[j].w += e * nb4[j].w;
        }
    }
#pragma unroll
    for (int m = 16; m <= 32; m <<= 1) {
        lsum += __shfl_xor(lsum, m);
#pragma unroll
        for (int j = 0; j < 4; ++j) {
            acc[j].x += __shfl_xor(acc[j].x, m);
            acc[j].y += __shfl_xor(acc[j].y, m);
            acc[j].z += __shfl_xor(acc[j].z, m);
            acc[j].w += __shfl_xor(acc[j].w, m);
        }
    }
    const float rl = 1.0f / lsum;
    if (g == 0) {
        float* ip = inbuf + (size_t)n * H;
        float* cp = cebuf + (size_t)n * H;
#pragma unroll
        for (int j = 0; j < 4; ++j) {
            float4 iv;
            iv.x = acc[j].x * rl + ce4[j].x;
            iv.y = acc[j].y * rl + ce4[j].y;
            iv.z = acc[j].z * rl + ce4[j].z;
            iv.w = acc[j].w * rl + ce4[j].w;
            *(float4*)(ip + hb + 64 * j) = iv;
            *(float4*)(cp + hb + 64 * j) = ce4[j];
        }
    }
}

// ---------------- Kernel B2: adapter rawret = elu(in@W1+b1)@W2 + b2 + ce ----
// 4 rows/wave, no LDS. matmul1: lane = b; the input row is wave-uniform so
// inb[h] compiles to s_load (SGPR broadcast, no readlane), W1[h][b] is a
// coalesced 256B load (L1/L2-hot, W1 = 64 KB). matmul2: lane = h-quad,
// hid broadcast via v_readlane.
__global__ __launch_bounds__(256) void kB2(
    float* __restrict__ io, const float* __restrict__ cebuf,
    const float* __restrict__ W1, const float* __restrict__ b1,
    const float* __restrict__ W2, const float* __restrict__ b2)
{
    const int tid = threadIdx.x;
    const int wv = tid >> 6, lane = tid & 63;
    const int r0 = __builtin_amdgcn_readfirstlane((blockIdx.x * 4 + wv) * 4);
    const float* inb = io + (size_t)r0 * H;

    float hid[4];
    const float bb = b1[lane];
#pragma unroll
    for (int r = 0; r < 4; ++r) hid[r] = bb;

#pragma unroll 8
    for (int h = 0; h < 256; ++h) {
        const float w1v = W1[h * 64 + lane];
        hid[0] += inb[h]           * w1v;
        hid[1] += inb[H + h]       * w1v;
        hid[2] += inb[2 * H + h]   * w1v;
        hid[3] += inb[3 * H + h]   * w1v;
    }
#pragma unroll
    for (int r = 0; r < 4; ++r)
        hid[r] = hid[r] > 0.f ? hid[r] : (__expf(hid[r]) - 1.0f);  // elu

    float4 p4[4];
    const float4 b2v = *(const float4*)(b2 + 4 * lane);
#pragma unroll
    for (int r = 0; r < 4; ++r) p4[r] = b2v;
#pragma unroll 4
    for (int b = 0; b < 64; ++b) {
        const float4 w2v = *(const float4*)(W2 + b * H + 4 * lane);
#pragma unroll
        for (int r = 0; r < 4; ++r) {
            const float hv = rdlane(hid[r], b);
            p4[r].x += hv * w2v.x; p4[r].y += hv * w2v.y;
            p4[r].z += hv * w2v.z; p4[r].w += hv * w2v.w;
        }
    }
#pragma unroll
    for (int r = 0; r < 4; ++r) {
        const float4 cev = *(const float4*)(cebuf + (size_t)(r0 + r) * H + 4 * lane);
        float4 ov;
        ov.x = p4[r].x + cev.x; ov.y = p4[r].y + cev.y;
        ov.z = p4[r].z + cev.z; ov.w = p4[r].w + cev.w;
        *(float4*)(io + (size_t)(r0 + r) * H + 4 * lane) = ov;
    }
}

// ---------------- Kernel C1: per-chunk per-class partial sums ---------------
__global__ __launch_bounds__(256) void kC1(
    const float* __restrict__ rawret, const int* __restrict__ labels,
    float* __restrict__ partial)
{
    const int t = threadIdx.x, j = blockIdx.x;
    const int nlo = j * CHUNK;
    const int nhi = min(nlo + CHUNK, NR);
    float acc[CC];
#pragma unroll
    for (int c = 0; c < CC; ++c) acc[c] = 0.f;
    for (int n = nlo; n < nhi; ++n) {
        const int lab = labels[n];
        const float v = rawret[(size_t)n * H + t];
#pragma unroll
        for (int c = 0; c < CC; ++c) acc[c] += (lab == c) ? v : 0.f;
    }
#pragma unroll
    for (int c = 0; c < CC; ++c) partial[(size_t)(j * CC + c) * H + t] = acc[c];
}

// ---------------- Kernel C2: finalize class means + norms -------------------
__global__ __launch_bounds__(256) void kC2(
    const float* __restrict__ partial, float* __restrict__ ave,
    float* __restrict__ anorm)
{
    const int c = blockIdx.x, t = threadIdx.x;
    float s = 0.f;
#pragma unroll 8
    for (int j = 0; j < GC1; ++j) s += partial[(size_t)(j * CC + c) * H + t];
    const float a = s * (1.0f / 2000.0f);   // per_class = N // C
    ave[c * H + t] = a;
    __shared__ float red[256];
    red[t] = a * a;
    __syncthreads();
    for (int m = 128; m > 0; m >>= 1) {
        if (t < m) red[t] += red[t + m];
        __syncthreads();
    }
    if (t == 0) anorm[c] = fmaxf(sqrtf(red[0]), EPSF);
}

// ---------------- Kernel D: class-cosine softmax -> out [N,7] ---------------
__global__ __launch_bounds__(256) void kD(
    const float* __restrict__ rawret, const float* __restrict__ ave,
    const float* __restrict__ anorm, float* __restrict__ out)
{
    const int tid = threadIdx.x;
    const int wv = tid >> 6, lane = tid & 63;
    const int n = blockIdx.x * 4 + wv;
    const float4 r4 = *(const float4*)(rawret + (size_t)n * H + 4 * lane);
    float nr2 = dot4(r4, r4);
#pragma unroll
    for (int m = 1; m <= 32; m <<= 1) nr2 += __shfl_xor(nr2, m);
    const float rn = fmaxf(sqrtf(nr2), EPSF);

    float e[CC];
    float s = 0.f;
#pragma unroll
    for (int c = 0; c < CC; ++c) {
        const float4 a4 = *(const float4*)(ave + c * H + 4 * lane);
        float d = dot4(r4, a4);
#pragma unroll
        for (int m = 1; m <= 32; m <<= 1) d += __shfl_xor(d, m);
        const float sim = d / (rn * anorm[c]);
        e[c] = __expf(sim - 1.0f);
        s += e[c];
    }
    const float rs = 1.0f / s;
    if (lane < CC) {
        float v = e[0];
#pragma unroll
        for (int c = 1; c < CC; ++c) v = (lane == c) ? e[c] : v;
        out[(size_t)n * CC + lane] = v * rs;
    }
}

extern "C" void kernel_launch(void* const* d_in, const int* in_sizes, int n_in,
                              void* d_out, int out_size, void* d_ws, size_t ws_size,
                              hipStream_t stream) {
    const float* embeds = (const float*)d_in[0];
    const float* w_self = (const float*)d_in[1];
    const float* w_n    = (const float*)d_in[2];
    const float* w_n2   = (const float*)d_in[3];
    const float* W1     = (const float*)d_in[4];
    const float* b1     = (const float*)d_in[5];
    const float* W2     = (const float*)d_in[6];
    const float* b2     = (const float*)d_in[7];
    const int* idx      = (const int*)d_in[8];
    const int* nbr1     = (const int*)d_in[9];
    const int* nbr2     = (const int*)d_in[10];
    const int* labels   = (const int*)d_in[11];
    float* out = (float*)d_out;

    float* buf0    = (float*)d_ws;                       // N*H: inputs -> rawret
    float* buf1    = buf0 + (size_t)NR * H;              // N*H: ce
    float* partial = buf1 + (size_t)NR * H;              // GC1*7*H
    float* ave     = partial + (size_t)GC1 * CC * H;     // 7*H
    float* anorm   = ave + (size_t)CC * H;               // 8 (padded)
    unsigned short* ebf = (unsigned short*)(anorm + 8);  // MR*H bf16 table

    const size_t need = ((char*)ebf - (char*)d_ws) + (size_t)MR * H * 2;

    if (ws_size >= need) {
        kE<<<(MR * H) / (256 * 8), 256, 0, stream>>>(embeds, ebf);
        kA2<<<NR / 4, 256, 0, stream>>>(embeds, ebf, w_self, w_n, w_n2,
                                        idx, nbr1, nbr2, buf0, buf1);
    } else {
        kA<<<NR / 4, 256, 0, stream>>>(embeds, w_self, w_n, w_n2,
                                       idx, nbr1, nbr2, buf0, buf1);
    }
    kB2<<<NR / 16, 256, 0, stream>>>(buf0, buf1, W1, b1, W2, b2);
    kC1<<<GC1, 256, 0, stream>>>(buf0, labels, partial);
    kC2<<<CC, 256, 0, stream>>>(partial, ave, anorm);
    kD<<<NR / 4, 256, 0, stream>>>(buf0, ave, anorm, out);
}